// Round 8
// baseline (1283.871 us; speedup 1.0000x reference)
//
#include <hip/hip_runtime.h>
#include <math.h>

#define N_NODES 50000
#define E_EDGES 800000
#define HDIM 256
#define NHEADS 8
#define HEADD 32
#define EDGED 3
#define NLAYERS 3

typedef unsigned int u32;
typedef unsigned short ushort_t;
typedef __attribute__((ext_vector_type(8))) short short8;
typedef __attribute__((ext_vector_type(8))) unsigned short ushort8v;
typedef __attribute__((ext_vector_type(4))) float float4v;

__device__ __forceinline__ float bf2f(ushort_t u) {
  union { u32 i; float f; } v;
  v.i = ((u32)u) << 16;
  return v.f;
}
// fp32 -> bf16 RNE
__device__ __forceinline__ ushort_t f2bf(float f) {
  u32 u = __float_as_uint(f);
  u = (u + 0x7FFF + ((u >> 16) & 1)) >> 16;
  return (ushort_t)u;
}

// ---------------------------------------------------------------------------
// edge_index layout detection (int64 vs int32 staging)
// ---------------------------------------------------------------------------
__global__ __launch_bounds__(256) void detect_idx_k(const u32* __restrict__ w,
                                                    int* __restrict__ flag) {
  __shared__ u32 sm[256];
  u32 mx = 0;
  for (int k = threadIdx.x; k < 4096; k += 256) mx = max(mx, w[2 * k + 1]);
  sm[threadIdx.x] = mx;
  __syncthreads();
  for (int s = 128; s > 0; s >>= 1) {
    if (threadIdx.x < s)
      sm[threadIdx.x] = max(sm[threadIdx.x], sm[threadIdx.x + s]);
    __syncthreads();
  }
  if (threadIdx.x == 0) flag[0] = (sm[0] == 0) ? 1 : 0;
}

__global__ __launch_bounds__(256) void convert_idx_k(
    const u32* __restrict__ w, const int* __restrict__ flag,
    int* __restrict__ src32, int* __restrict__ dst32, int E_) {
  int e = blockIdx.x * blockDim.x + threadIdx.x;
  if (e >= E_) return;
  if (flag[0]) {
    src32[e] = (int)w[2 * e];
    dst32[e] = (int)w[2 * (E_ + e)];
  } else {
    src32[e] = (int)w[e];
    dst32[e] = (int)w[E_ + e];
  }
}

// ---------------------------------------------------------------------------
// CSR build: histogram, 3-phase scan, scatter
// ---------------------------------------------------------------------------
__global__ __launch_bounds__(256) void hist_k(const int* __restrict__ dst,
                                              int* __restrict__ dcnt, int E_) {
  int e = blockIdx.x * blockDim.x + threadIdx.x;
  if (e >= E_) return;
  atomicAdd(&dcnt[dst[e]], 1);
}

__global__ __launch_bounds__(256) void scan1_k(const int* __restrict__ deg,
                                               int* __restrict__ scanned,
                                               int* __restrict__ bsum, int n) {
  __shared__ int tmp[256];
  int tid = threadIdx.x;
  int i = blockIdx.x * 256 + tid;
  tmp[tid] = (i < n) ? deg[i] : 0;
  __syncthreads();
  for (int off = 1; off < 256; off <<= 1) {
    int t = (tid >= off) ? tmp[tid - off] : 0;
    __syncthreads();
    tmp[tid] += t;
    __syncthreads();
  }
  if (i < n) scanned[i] = tmp[tid];
  if (tid == 255) bsum[blockIdx.x] = tmp[255];
}

__global__ __launch_bounds__(256) void scan2_k(int* __restrict__ bsum, int nb) {
  __shared__ int tmp[256];
  int tid = threadIdx.x;
  tmp[tid] = (tid < nb) ? bsum[tid] : 0;
  __syncthreads();
  for (int off = 1; off < 256; off <<= 1) {
    int t = (tid >= off) ? tmp[tid - off] : 0;
    __syncthreads();
    tmp[tid] += t;
    __syncthreads();
  }
  if (tid < nb) bsum[tid] = tmp[tid];
}

__global__ __launch_bounds__(256) void scan3_k(const int* __restrict__ scanned,
                                               const int* __restrict__ bsum,
                                               int* __restrict__ rowptr, int n) {
  int i = blockIdx.x * 256 + threadIdx.x;
  if (i < n)
    rowptr[i + 1] = scanned[i] + (blockIdx.x > 0 ? bsum[blockIdx.x - 1] : 0);
  if (i == 0) rowptr[0] = 0;
}

__global__ __launch_bounds__(256) void fill_k(
    const int* __restrict__ srcI, const int* __restrict__ dstI,
    const int* __restrict__ rowptr, int* __restrict__ cursor,
    int* __restrict__ src_sorted, int* __restrict__ eorig, int E_) {
  int e = blockIdx.x * blockDim.x + threadIdx.x;
  if (e >= E_) return;
  int d = dstI[e];
  int p = rowptr[d] + atomicAdd(&cursor[d], 1);
  src_sorted[p] = srcI[e];
  eorig[p] = e;
}

// ---------------------------------------------------------------------------
// Weight transpose+convert: W (K x N fp32) -> WT (N x K bf16), tile 16k x 64n
// ---------------------------------------------------------------------------
__global__ __launch_bounds__(256) void wtrans_k(const float* __restrict__ W,
                                                ushort_t* __restrict__ WT,
                                                int K, int N) {
  __shared__ float t[64][17];
  int k0 = blockIdx.x * 16, n0 = blockIdx.y * 64;
  int tid = threadIdx.x;
  int r = tid >> 6, c = tid & 63;
#pragma unroll
  for (int i = 0; i < 4; ++i)
    t[c][r + 4 * i] = W[(size_t)(k0 + r + 4 * i) * N + n0 + c];
  __syncthreads();
  int n = tid >> 2, j4 = (tid & 3) * 4;
  ushort4 o;
  o.x = f2bf(t[n][j4 + 0]);
  o.y = f2bf(t[n][j4 + 1]);
  o.z = f2bf(t[n][j4 + 2]);
  o.w = f2bf(t[n][j4 + 3]);
  *(ushort4*)&WT[(size_t)(n0 + n) * K + k0 + j4] = o;
}

// ---------------------------------------------------------------------------
// Input projection: h = relu(x @ W_in + b_in); writes fp32 h AND bf16 hbf
// ---------------------------------------------------------------------------
__global__ __launch_bounds__(256) void input_proj_k(
    const float* __restrict__ x, const float* __restrict__ W,
    const float* __restrict__ b, float* __restrict__ h,
    ushort_t* __restrict__ hbf, int n) {
  __shared__ float ws[10 * 256];
  __shared__ float bs[256];
  int tid = threadIdx.x;
  for (int i = tid; i < 2560; i += 256) ws[i] = W[i];
  bs[tid] = b[tid];
  __syncthreads();
  int row0 = blockIdx.x * 32;
  for (int rr = 0; rr < 32; ++rr) {
    int row = row0 + rr;
    if (row >= n) break;
    float acc = bs[tid];
#pragma unroll
    for (int i = 0; i < 10; ++i) acc += x[row * 10 + i] * ws[i * 256 + tid];
    acc = fmaxf(acc, 0.f);
    h[(size_t)row * 256 + tid] = acc;
    hbf[(size_t)row * 256 + tid] = f2bf(acc);
  }
}

// ---------------------------------------------------------------------------
// bf16 MFMA GEMM, 128x128 tile: C = act(A @ B + bias)
// A1 (M x K1 bf16 row-major); if CONCAT logical A = [A1|A2], Ktot = 2*K1.
// BT (Ncol x Ktot bf16, n-major k-contig). bias fp32 or null.
// 256 thr = 4 waves; BK=32; wave w: rows [32w,32w+32) x all 128 cols,
// 2 a-frags x 8 b-frags = 16 mfma_f32_16x16x32_bf16 per BK chunk.
// ---------------------------------------------------------------------------
template <bool CONCAT, bool RELU, bool OUTBF>
__global__ __launch_bounds__(256) void gemm_mfma_k(
    const ushort_t* __restrict__ A1, const ushort_t* __restrict__ A2,
    const ushort_t* __restrict__ BT, const float* __restrict__ bias,
    void* __restrict__ Cout, int M, int K1, int Ktot, int Ncol) {
  __shared__ __align__(16) ushort_t Als[128 * 32];
  __shared__ __align__(16) ushort_t Bls[128 * 32];
  int tid = threadIdx.x;
  int lane = tid & 63, w = tid >> 6;
  int quad = lane >> 4, m = lane & 15;
  int row0 = blockIdx.y * 128, col0 = blockIdx.x * 128;
  float4v acc[2][8];
#pragma unroll
  for (int t = 0; t < 2; ++t)
#pragma unroll
    for (int j = 0; j < 8; ++j) acc[t][j] = (float4v){0.f, 0.f, 0.f, 0.f};

  int arow = tid >> 1, ahalf = (tid & 1) * 16;  // A: 16 bf16 per thread

  for (int k0 = 0; k0 < Ktot; k0 += 32) {
    const ushort_t* Ap = A1;
    int kk = k0;
    if (CONCAT && k0 >= K1) { Ap = A2; kk = k0 - K1; }
    int r = row0 + arow;
    if (r < M) {
      const ushort_t* s = Ap + (size_t)r * K1 + kk + ahalf;
      *(ushort8v*)&Als[arow * 32 + ahalf] = *(const ushort8v*)s;
      *(ushort8v*)&Als[arow * 32 + ahalf + 8] = *(const ushort8v*)(s + 8);
    } else {
#pragma unroll
      for (int i = 0; i < 16; ++i) Als[arow * 32 + ahalf + i] = 0;
    }
    {
      const ushort_t* s = BT + (size_t)(col0 + arow) * Ktot + k0 + ahalf;
      *(ushort8v*)&Bls[arow * 32 + ahalf] = *(const ushort8v*)s;
      *(ushort8v*)&Bls[arow * 32 + ahalf + 8] = *(const ushort8v*)(s + 8);
    }
    __syncthreads();
    short8 a0 = *(const short8*)&Als[(w * 32 + m) * 32 + quad * 8];
    short8 a1 = *(const short8*)&Als[(w * 32 + 16 + m) * 32 + quad * 8];
#pragma unroll
    for (int j = 0; j < 8; ++j) {
      short8 bj = *(const short8*)&Bls[(16 * j + m) * 32 + quad * 8];
      acc[0][j] = __builtin_amdgcn_mfma_f32_16x16x32_bf16(a0, bj, acc[0][j], 0, 0, 0);
      acc[1][j] = __builtin_amdgcn_mfma_f32_16x16x32_bf16(a1, bj, acc[1][j], 0, 0, 0);
    }
    __syncthreads();
  }

#pragma unroll
  for (int t = 0; t < 2; ++t) {
#pragma unroll
    for (int j = 0; j < 8; ++j) {
      int col = col0 + 16 * j + m;
      float bv = bias ? bias[col] : 0.f;
#pragma unroll
      for (int rr = 0; rr < 4; ++rr) {
        int row = row0 + w * 32 + 16 * t + quad * 4 + rr;
        if (row >= M) continue;
        float v = acc[t][j][rr] + bv;
        if (RELU) v = fmaxf(v, 0.f);
        if (OUTBF)
          ((ushort_t*)Cout)[(size_t)row * Ncol + col] = f2bf(v);
        else
          ((float*)Cout)[(size_t)row * Ncol + col] = v;
      }
    }
  }
}

// ---------------------------------------------------------------------------
// FUSED edge phase: per-node online-softmax attention + V aggregation.
// One wave per node; QUARTER-wave (16 lanes) per edge slot => 4 edges in
// flight. Lane ql covers dims [16ql,16ql+16) via 2x ushort8 loads; head =
// ql>>1 (2 lanes per 32-dim head, dot completed by shfl_xor 1).
// Per-node online max (mathematically equal to reference's global-max form).
// QKV row stride 768 (Q | K | V). agg out bf16 (N x 256).
// ---------------------------------------------------------------------------
__global__ __launch_bounds__(256) void node_fused_k(
    const ushort_t* __restrict__ QKV, const float* __restrict__ ea,
    const float* __restrict__ We_l, const int* __restrict__ rowptr,
    const int* __restrict__ src_sorted, const int* __restrict__ eorig,
    ushort_t* __restrict__ agg, int n) {
  int node = (blockIdx.x * blockDim.x + threadIdx.x) >> 6;
  if (node >= n) return;
  int lane = threadIdx.x & 63;
  int ql = lane & 15;   // lane within quarter-wave
  int slot = lane >> 4; // which of 4 concurrent edges
  const ushort8v* qp = (const ushort8v*)(QKV + (size_t)node * 768 + ql * 16);
  ushort8v qa = qp[0], qb = qp[1];
  float q[16];
#pragma unroll
  for (int i = 0; i < 8; ++i) { q[i] = bf2f(qa[i]); q[8 + i] = bf2f(qb[i]); }
  int start = rowptr[node], end = rowptr[node + 1];
  int hh = ql >> 1;
  float w0 = We_l[0 * 8 + hh], w1 = We_l[1 * 8 + hh], w2 = We_l[2 * 8 + hh];
  float m = -INFINITY, l = 0.f;
  float acc[16];
#pragma unroll
  for (int i = 0; i < 16; ++i) acc[i] = 0.f;

  int iters = (end - start + 3) >> 2;
  for (int it = 0; it < iters; ++it) {
    int p = start + 4 * it + slot;
    if (p < end) {
      int s = src_sorted[p];
      const ushort_t* base = QKV + (size_t)s * 768 + ql * 16;
      const ushort8v* kp = (const ushort8v*)(base + 256);
      const ushort8v* vp = (const ushort8v*)(base + 512);
      ushort8v ka = kp[0], kb = kp[1];
      ushort8v va = vp[0], vb = vp[1];
      float d = 0.f;
#pragma unroll
      for (int i = 0; i < 8; ++i) d += q[i] * bf2f(ka[i]);
#pragma unroll
      for (int i = 0; i < 8; ++i) d += q[8 + i] * bf2f(kb[i]);
      d += __shfl_xor(d, 1);  // complete 32-dim head dot across lane pair
      int e = eorig[p];
      float bias = ea[(size_t)e * 3 + 0] * w0 + ea[(size_t)e * 3 + 1] * w1 +
                   ea[(size_t)e * 3 + 2] * w2;
      float a = d * 0.17677669529663687f + bias;  // 1/sqrt(32)
      a = (a > 0.f) ? a : 0.2f * a;               // leaky_relu 0.2
      float mn = fmaxf(m, a);
      float sc = __expf(m - mn);  // m=-inf first time -> 0
      float wv = __expf(a - mn);
      l = l * sc + wv;
#pragma unroll
      for (int i = 0; i < 8; ++i) acc[i] = acc[i] * sc + bf2f(va[i]) * wv;
#pragma unroll
      for (int i = 0; i < 8; ++i)
        acc[8 + i] = acc[8 + i] * sc + bf2f(vb[i]) * wv;
      m = mn;
    }
  }
  // merge the 4 slot states (xor 16, then xor 32)
#pragma unroll
  for (int off = 16; off <= 32; off <<= 1) {
    float m2 = __shfl_xor(m, off);
    float l2 = __shfl_xor(l, off);
    float mn = fmaxf(m, m2);
    float mne = fmaxf(mn, -1e30f);  // degree-0 guard: exp(-inf-(-1e30))=0
    float s1 = __expf(m - mne), s2 = __expf(m2 - mne);
    l = l * s1 + l2 * s2;
#pragma unroll
    for (int i = 0; i < 16; ++i)
      acc[i] = acc[i] * s1 + __shfl_xor(acc[i], off) * s2;
    m = mn;
  }
  float inv = 1.f / fmaxf(l, 1e-12f);
  if (slot == 0) {
    ushort8v oa, ob;
#pragma unroll
    for (int i = 0; i < 8; ++i) {
      oa[i] = f2bf(acc[i] * inv);
      ob[i] = f2bf(acc[8 + i] * inv);
    }
    ushort8v* op = (ushort8v*)(agg + (size_t)node * 256 + ql * 16);
    op[0] = oa;
    op[1] = ob;
  }
}

// ---------------------------------------------------------------------------
// h = LayerNorm(h + upd)*gamma+beta (in-place); also writes bf16 hbf
// ---------------------------------------------------------------------------
__global__ __launch_bounds__(256) void add_ln_k(
    float* __restrict__ h, const float* __restrict__ upd,
    const float* __restrict__ g, const float* __restrict__ b,
    ushort_t* __restrict__ hbf, int n) {
  int row = (blockIdx.x * blockDim.x + threadIdx.x) >> 6;
  if (row >= n) return;
  int lane = threadIdx.x & 63;
  float4 hv = ((const float4*)(h + (size_t)row * 256))[lane];
  float4 uv = ((const float4*)(upd + (size_t)row * 256))[lane];
  float4 s = make_float4(hv.x + uv.x, hv.y + uv.y, hv.z + uv.z, hv.w + uv.w);
  float sum = s.x + s.y + s.z + s.w;
  float sq = s.x * s.x + s.y * s.y + s.z * s.z + s.w * s.w;
  for (int d = 1; d < 64; d <<= 1) {
    sum += __shfl_xor(sum, d);
    sq += __shfl_xor(sq, d);
  }
  float mean = sum * (1.f / 256.f);
  float var = sq * (1.f / 256.f) - mean * mean;
  float r = rsqrtf(var + 1e-5f);
  float4 g4 = ((const float4*)g)[lane];
  float4 b4 = ((const float4*)b)[lane];
  float4 o;
  o.x = (s.x - mean) * r * g4.x + b4.x;
  o.y = (s.y - mean) * r * g4.y + b4.y;
  o.z = (s.z - mean) * r * g4.z + b4.z;
  o.w = (s.w - mean) * r * g4.w + b4.w;
  ((float4*)(h + (size_t)row * 256))[lane] = o;
  ushort4 ob;
  ob.x = f2bf(o.x);
  ob.y = f2bf(o.y);
  ob.z = f2bf(o.z);
  ob.w = f2bf(o.w);
  ((ushort4*)(hbf + (size_t)row * 256))[lane] = ob;
}

// ---------------------------------------------------------------------------
// out[n] = t[n,:128] @ W_h2 + b_h2 — one wave per row; fp32 out
// ---------------------------------------------------------------------------
__global__ __launch_bounds__(256) void head2_k(
    const float* __restrict__ t, const float* __restrict__ W2,
    const float* __restrict__ b2, float* __restrict__ out, int n) {
  int row = (blockIdx.x * blockDim.x + threadIdx.x) >> 6;
  if (row >= n) return;
  int lane = threadIdx.x & 63;
  float acc = t[(size_t)row * 128 + lane] * W2[lane] +
              t[(size_t)row * 128 + 64 + lane] * W2[64 + lane];
  for (int d = 1; d < 64; d <<= 1) acc += __shfl_xor(acc, d);
  if (lane == 0) out[row] = acc + b2[0];
}

// ---------------------------------------------------------------------------
extern "C" void kernel_launch(void* const* d_in, const int* in_sizes, int n_in,
                              void* d_out, int out_size, void* d_ws,
                              size_t ws_size, hipStream_t stream) {
  const float* x = (const float*)d_in[0];
  const float* edge_attr = (const float*)d_in[1];
  const float* W_in = (const float*)d_in[2];
  const float* b_in = (const float*)d_in[3];
  const float* Wq = (const float*)d_in[4];
  const float* Wk = (const float*)d_in[5];
  const float* Wv = (const float*)d_in[6];
  const float* We = (const float*)d_in[7];
  const float* Wo = (const float*)d_in[8];
  const float* bo = (const float*)d_in[9];
  const float* Wm = (const float*)d_in[10];
  const float* bm = (const float*)d_in[11];
  const float* gamma = (const float*)d_in[12];
  const float* beta = (const float*)d_in[13];
  const float* W_h1 = (const float*)d_in[14];
  const float* b_h1 = (const float*)d_in[15];
  const float* W_h2 = (const float*)d_in[16];
  const float* b_h2 = (const float*)d_in[17];
  const u32* eidx_w = (const u32*)d_in[18];

  // ws layout (~214 MB, proven-safe <= 238 MB)
  float* ws = (float*)d_ws;
  const size_t NH_ = (size_t)N_NODES * HDIM;
  float* h = ws;
  ushort_t* hbf = (ushort_t*)(h + NH_);
  ushort_t* QKVbf = hbf + NH_;              // N x 768
  ushort_t* aggbf = QKVbf + (size_t)N_NODES * 768;
  ushort_t* tmpbf = aggbf + NH_;
  float* Ub = (float*)QKVbf;                // N x 256 f32 (overlay)
  float* tH = (float*)QKVbf;                // N x 128 f32 (overlay)
  int* idxflag = (int*)(tmpbf + NH_);
  int* src_sorted = idxflag + 1;            // E
  int* eorig = src_sorted + E_EDGES;        // E
  int* rowptr = eorig + E_EDGES;            // N+1
  int* dcnt = rowptr + N_NODES + 1;         // N
  int* scanned = dcnt + N_NODES;            // N
  int* bsum = scanned + N_NODES;            // 256
  ushort_t* WT = (ushort_t*)(bsum + 256);
  const size_t W64K = (size_t)HDIM * HDIM;
  const size_t W128K = (size_t)2 * HDIM * HDIM;
  ushort_t* WqkvT = WT;                     // 3 layers x (768 x 256)
  ushort_t* WoT = WqkvT + 3 * 3 * W64K;
  ushort_t* WmT = WoT + 3 * W64K;
  ushort_t* Wh1T = WmT + 3 * W128K;
  // transient: consumed by fill_k before any GEMM writes QKVbf
  int* srcI = (int*)QKVbf;
  int* dstI = srcI + E_EDGES;

  detect_idx_k<<<1, 256, 0, stream>>>(eidx_w, idxflag);
  convert_idx_k<<<(E_EDGES + 255) / 256, 256, 0, stream>>>(
      eidx_w, idxflag, srcI, dstI, E_EDGES);

  // CSR build
  hipMemsetAsync(dcnt, 0, (size_t)N_NODES * sizeof(int), stream);
  hist_k<<<(E_EDGES + 255) / 256, 256, 0, stream>>>(dstI, dcnt, E_EDGES);
  const int nsb = (N_NODES + 255) / 256;
  scan1_k<<<nsb, 256, 0, stream>>>(dcnt, scanned, bsum, N_NODES);
  scan2_k<<<1, 256, 0, stream>>>(bsum, nsb);
  scan3_k<<<nsb, 256, 0, stream>>>(scanned, bsum, rowptr, N_NODES);
  hipMemsetAsync(dcnt, 0, (size_t)N_NODES * sizeof(int), stream);
  fill_k<<<(E_EDGES + 255) / 256, 256, 0, stream>>>(
      srcI, dstI, rowptr, dcnt, src_sorted, eorig, E_EDGES);

  // weight transpose+convert; QKV concatenated along N (rows of BT)
  for (int l = 0; l < NLAYERS; ++l) {
    ushort_t* base = WqkvT + (size_t)l * 3 * W64K;
    wtrans_k<<<dim3(16, 4), 256, 0, stream>>>(Wq + l * W64K, base, HDIM, HDIM);
    wtrans_k<<<dim3(16, 4), 256, 0, stream>>>(Wk + l * W64K, base + W64K, HDIM,
                                              HDIM);
    wtrans_k<<<dim3(16, 4), 256, 0, stream>>>(Wv + l * W64K, base + 2 * W64K,
                                              HDIM, HDIM);
    wtrans_k<<<dim3(16, 4), 256, 0, stream>>>(Wo + l * W64K, WoT + l * W64K,
                                              HDIM, HDIM);
    wtrans_k<<<dim3(32, 4), 256, 0, stream>>>(Wm + l * W128K, WmT + l * W128K,
                                              2 * HDIM, HDIM);
  }
  wtrans_k<<<dim3(16, 2), 256, 0, stream>>>(W_h1, Wh1T, HDIM, HDIM / 2);

  input_proj_k<<<(N_NODES + 31) / 32, 256, 0, stream>>>(x, W_in, b_in, h, hbf,
                                                        N_NODES);
  dim3 gqkv(768 / 128, (N_NODES + 127) / 128);  // (6, 391)
  dim3 gg(HDIM / 128, (N_NODES + 127) / 128);   // (2, 391)
  const int nodewave_grid = (N_NODES * 64 + 255) / 256;

  for (int l = 0; l < NLAYERS; ++l) {
    const float* We_l = We + (size_t)l * EDGED * NHEADS;
    const float* bo_l = bo + (size_t)l * HDIM;
    const float* bm_l = bm + (size_t)l * HDIM;

    // QKV = hbf @ [Wq|Wk|Wv]  (N x 768 bf16)
    gemm_mfma_k<false, false, true><<<gqkv, 256, 0, stream>>>(
        hbf, nullptr, WqkvT + (size_t)l * 3 * W64K, nullptr, QKVbf, N_NODES,
        HDIM, HDIM, 768);
    // fused attention + softmax + aggregation
    node_fused_k<<<nodewave_grid, 256, 0, stream>>>(
        QKVbf, edge_attr, We_l, rowptr, src_sorted, eorig, aggbf, N_NODES);
    // tmp = agg @ Wo + bo (bf16)
    gemm_mfma_k<false, false, true><<<gg, 256, 0, stream>>>(
        aggbf, nullptr, WoT + l * W64K, bo_l, tmpbf, N_NODES, HDIM, HDIM,
        HDIM);
    // upd = relu([hbf|tmpbf] @ Wm + bm) fp32 -> Ub (overlays QKVbf, dead)
    gemm_mfma_k<true, true, false><<<gg, 256, 0, stream>>>(
        hbf, tmpbf, WmT + l * W128K, bm_l, Ub, N_NODES, HDIM, 2 * HDIM, HDIM);
    add_ln_k<<<nodewave_grid, 256, 0, stream>>>(
        h, Ub, gamma + (size_t)l * HDIM, beta + (size_t)l * HDIM, hbf, N_NODES);
  }
  // head: t = relu(hbf @ W_h1 + b_h1) fp32 -> tH (overlays QKVbf)
  dim3 gh(1, (N_NODES + 127) / 128);
  gemm_mfma_k<false, true, false><<<gh, 256, 0, stream>>>(
      hbf, nullptr, Wh1T, b_h1, tH, N_NODES, HDIM, HDIM, HDIM / 2);
  head2_k<<<nodewave_grid, 256, 0, stream>>>(tH, W_h2, b_h2, (float*)d_out,
                                             N_NODES);
}

// Round 9
// 1151.549 us; speedup vs baseline: 1.1149x; 1.1149x over previous
//
#include <hip/hip_runtime.h>
#include <math.h>

#define N_NODES 50000
#define E_EDGES 800000
#define HDIM 256
#define NHEADS 8
#define HEADD 32
#define EDGED 3
#define NLAYERS 3

typedef unsigned int u32;
typedef unsigned short ushort_t;
typedef __attribute__((ext_vector_type(8))) short short8;
typedef __attribute__((ext_vector_type(8))) unsigned short ushort8v;
typedef __attribute__((ext_vector_type(4))) float float4v;

typedef __attribute__((address_space(1))) const void* gas_p;
typedef __attribute__((address_space(3))) void* las_p;

__device__ __forceinline__ float bf2f(ushort_t u) {
  union { u32 i; float f; } v;
  v.i = ((u32)u) << 16;
  return v.f;
}
// fp32 -> bf16 RNE
__device__ __forceinline__ ushort_t f2bf(float f) {
  u32 u = __float_as_uint(f);
  u = (u + 0x7FFF + ((u >> 16) & 1)) >> 16;
  return (ushort_t)u;
}

// ---------------------------------------------------------------------------
// edge_index layout detection (int64 vs int32 staging)
// ---------------------------------------------------------------------------
__global__ __launch_bounds__(256) void detect_idx_k(const u32* __restrict__ w,
                                                    int* __restrict__ flag) {
  __shared__ u32 sm[256];
  u32 mx = 0;
  for (int k = threadIdx.x; k < 4096; k += 256) mx = max(mx, w[2 * k + 1]);
  sm[threadIdx.x] = mx;
  __syncthreads();
  for (int s = 128; s > 0; s >>= 1) {
    if (threadIdx.x < s)
      sm[threadIdx.x] = max(sm[threadIdx.x], sm[threadIdx.x + s]);
    __syncthreads();
  }
  if (threadIdx.x == 0) flag[0] = (sm[0] == 0) ? 1 : 0;
}

__global__ __launch_bounds__(256) void convert_idx_k(
    const u32* __restrict__ w, const int* __restrict__ flag,
    int* __restrict__ src32, int* __restrict__ dst32, int E_) {
  int e = blockIdx.x * blockDim.x + threadIdx.x;
  if (e >= E_) return;
  if (flag[0]) {
    src32[e] = (int)w[2 * e];
    dst32[e] = (int)w[2 * (E_ + e)];
  } else {
    src32[e] = (int)w[e];
    dst32[e] = (int)w[E_ + e];
  }
}

// ---------------------------------------------------------------------------
// CSR build: histogram, 3-phase scan, scatter
// ---------------------------------------------------------------------------
__global__ __launch_bounds__(256) void hist_k(const int* __restrict__ dst,
                                              int* __restrict__ dcnt, int E_) {
  int e = blockIdx.x * blockDim.x + threadIdx.x;
  if (e >= E_) return;
  atomicAdd(&dcnt[dst[e]], 1);
}

__global__ __launch_bounds__(256) void scan1_k(const int* __restrict__ deg,
                                               int* __restrict__ scanned,
                                               int* __restrict__ bsum, int n) {
  __shared__ int tmp[256];
  int tid = threadIdx.x;
  int i = blockIdx.x * 256 + tid;
  tmp[tid] = (i < n) ? deg[i] : 0;
  __syncthreads();
  for (int off = 1; off < 256; off <<= 1) {
    int t = (tid >= off) ? tmp[tid - off] : 0;
    __syncthreads();
    tmp[tid] += t;
    __syncthreads();
  }
  if (i < n) scanned[i] = tmp[tid];
  if (tid == 255) bsum[blockIdx.x] = tmp[255];
}

__global__ __launch_bounds__(256) void scan2_k(int* __restrict__ bsum, int nb) {
  __shared__ int tmp[256];
  int tid = threadIdx.x;
  tmp[tid] = (tid < nb) ? bsum[tid] : 0;
  __syncthreads();
  for (int off = 1; off < 256; off <<= 1) {
    int t = (tid >= off) ? tmp[tid - off] : 0;
    __syncthreads();
    tmp[tid] += t;
    __syncthreads();
  }
  if (tid < nb) bsum[tid] = tmp[tid];
}

__global__ __launch_bounds__(256) void scan3_k(const int* __restrict__ scanned,
                                               const int* __restrict__ bsum,
                                               int* __restrict__ rowptr, int n) {
  int i = blockIdx.x * 256 + threadIdx.x;
  if (i < n)
    rowptr[i + 1] = scanned[i] + (blockIdx.x > 0 ? bsum[blockIdx.x - 1] : 0);
  if (i == 0) rowptr[0] = 0;
}

__global__ __launch_bounds__(256) void fill_k(
    const int* __restrict__ srcI, const int* __restrict__ dstI,
    const int* __restrict__ rowptr, int* __restrict__ cursor,
    int* __restrict__ src_sorted, int* __restrict__ eorig, int E_) {
  int e = blockIdx.x * blockDim.x + threadIdx.x;
  if (e >= E_) return;
  int d = dstI[e];
  int p = rowptr[d] + atomicAdd(&cursor[d], 1);
  src_sorted[p] = srcI[e];
  eorig[p] = e;
}

// ---------------------------------------------------------------------------
// Weight transpose+convert: W (K x N fp32) -> WT (N x K bf16), tile 16k x 64n
// blockIdx.z = matrix index (W += z*K*N, WT += z*N*K).
// ---------------------------------------------------------------------------
__global__ __launch_bounds__(256) void wtrans_k(const float* __restrict__ W,
                                                ushort_t* __restrict__ WT,
                                                int K, int N) {
  W += (size_t)blockIdx.z * K * N;
  WT += (size_t)blockIdx.z * N * K;
  __shared__ float t[64][17];
  int k0 = blockIdx.x * 16, n0 = blockIdx.y * 64;
  int tid = threadIdx.x;
  int r = tid >> 6, c = tid & 63;
#pragma unroll
  for (int i = 0; i < 4; ++i)
    t[c][r + 4 * i] = W[(size_t)(k0 + r + 4 * i) * N + n0 + c];
  __syncthreads();
  int n = tid >> 2, j4 = (tid & 3) * 4;
  ushort4 o;
  o.x = f2bf(t[n][j4 + 0]);
  o.y = f2bf(t[n][j4 + 1]);
  o.z = f2bf(t[n][j4 + 2]);
  o.w = f2bf(t[n][j4 + 3]);
  *(ushort4*)&WT[(size_t)(n0 + n) * K + k0 + j4] = o;
}

// batched Wq/Wk/Wv/Wo transpose: blockIdx.z = l*4 + m (m: 0=q,1=k,2=v,3=o)
__global__ __launch_bounds__(256) void wtrans_qkvo_k(
    const float* __restrict__ Wq, const float* __restrict__ Wk,
    const float* __restrict__ Wv, const float* __restrict__ Wo,
    ushort_t* __restrict__ WqkvT, ushort_t* __restrict__ WoT) {
  const size_t W64K = 65536;
  int z = blockIdx.z, l = z >> 2, m = z & 3;
  const float* W =
      (m == 0 ? Wq : m == 1 ? Wk : m == 2 ? Wv : Wo) + (size_t)l * W64K;
  ushort_t* WT = (m < 3) ? (WqkvT + ((size_t)l * 3 + m) * W64K)
                         : (WoT + (size_t)l * W64K);
  __shared__ float t[64][17];
  int k0 = blockIdx.x * 16, n0 = blockIdx.y * 64;
  int tid = threadIdx.x;
  int r = tid >> 6, c = tid & 63;
#pragma unroll
  for (int i = 0; i < 4; ++i)
    t[c][r + 4 * i] = W[(size_t)(k0 + r + 4 * i) * 256 + n0 + c];
  __syncthreads();
  int n = tid >> 2, j4 = (tid & 3) * 4;
  ushort4 o;
  o.x = f2bf(t[n][j4 + 0]);
  o.y = f2bf(t[n][j4 + 1]);
  o.z = f2bf(t[n][j4 + 2]);
  o.w = f2bf(t[n][j4 + 3]);
  *(ushort4*)&WT[(size_t)(n0 + n) * 256 + k0 + j4] = o;
}

// ---------------------------------------------------------------------------
// Input projection: h = relu(x @ W_in + b_in); writes fp32 h AND bf16 hbf
// ---------------------------------------------------------------------------
__global__ __launch_bounds__(256) void input_proj_k(
    const float* __restrict__ x, const float* __restrict__ W,
    const float* __restrict__ b, float* __restrict__ h,
    ushort_t* __restrict__ hbf, int n) {
  __shared__ float ws[10 * 256];
  __shared__ float bs[256];
  int tid = threadIdx.x;
  for (int i = tid; i < 2560; i += 256) ws[i] = W[i];
  bs[tid] = b[tid];
  __syncthreads();
  int row0 = blockIdx.x * 32;
  for (int rr = 0; rr < 32; ++rr) {
    int row = row0 + rr;
    if (row >= n) break;
    float acc = bs[tid];
#pragma unroll
    for (int i = 0; i < 10; ++i) acc += x[row * 10 + i] * ws[i * 256 + tid];
    acc = fmaxf(acc, 0.f);
    h[(size_t)row * 256 + tid] = acc;
    hbf[(size_t)row * 256 + tid] = f2bf(acc);
  }
}

// ---------------------------------------------------------------------------
// bf16 MFMA GEMM, 128x64 tile (R7-proven fragment math) with async
// global_load_lds width=16 staging (m97 ladder step).
// A1 (M x K1 bf16 row-major); if CONCAT logical A = [A1|A2], Ktot = 2*K1.
// BT (Ncol x Ktot bf16, n-major k-contig). bias fp32 or null.
// LDS layout: Als row stride 64B; staged as LDS_byte = tid*16 (+4096 for
// rows 64..127) == wave-uniform base (w*1024) + lane*16  -> fits the
// global_load_lds wave-uniform-base constraint. OOB rows exec-masked off;
// their garbage LDS rows are never stored (epilogue row guard).
// ---------------------------------------------------------------------------
template <bool CONCAT, bool RELU, bool OUTBF>
__global__ __launch_bounds__(256) void gemm_mfma_k(
    const ushort_t* __restrict__ A1, const ushort_t* __restrict__ A2,
    const ushort_t* __restrict__ BT, const float* __restrict__ bias,
    void* __restrict__ Cout, int M, int K1, int Ktot, int Ncol) {
  __shared__ __align__(16) ushort_t Als[128 * 32];
  __shared__ __align__(16) ushort_t Bls[64 * 32];
  int tid = threadIdx.x;
  int lane = tid & 63, w = tid >> 6;
  int quad = lane >> 4, m = lane & 15;
  int row0 = blockIdx.y * 128, col0 = blockIdx.x * 64;
  float4v acc[2][4];
#pragma unroll
  for (int t = 0; t < 2; ++t)
#pragma unroll
    for (int j = 0; j < 4; ++j) acc[t][j] = (float4v){0.f, 0.f, 0.f, 0.f};

  int srow = tid >> 2;          // 0..63 (staging row within half-tile)
  int skc = (tid & 3) * 8;      // k-offset, 8 ushorts = 16 B
  char* alsb = (char*)Als + w * 1024;  // wave-uniform LDS base
  char* blsb = (char*)Bls + w * 1024;

  for (int k0 = 0; k0 < Ktot; k0 += 32) {
    const ushort_t* Ap = A1;
    int kk = k0;
    if (CONCAT && k0 >= K1) { Ap = A2; kk = k0 - K1; }
#pragma unroll
    for (int q = 0; q < 2; ++q) {
      int r = row0 + 64 * q + srow;
      if (r < M) {
        const ushort_t* g = Ap + (size_t)r * K1 + kk + skc;
        __builtin_amdgcn_global_load_lds((gas_p)g, (las_p)(alsb + q * 4096),
                                         16, 0, 0);
      }
    }
    {
      const ushort_t* g = BT + (size_t)(col0 + srow) * Ktot + k0 + skc;
      __builtin_amdgcn_global_load_lds((gas_p)g, (las_p)blsb, 16, 0, 0);
    }
    __syncthreads();
    short8 a0 = *(const short8*)&Als[(w * 32 + m) * 32 + quad * 8];
    short8 a1 = *(const short8*)&Als[(w * 32 + 16 + m) * 32 + quad * 8];
#pragma unroll
    for (int j = 0; j < 4; ++j) {
      short8 bj = *(const short8*)&Bls[(16 * j + m) * 32 + quad * 8];
      acc[0][j] = __builtin_amdgcn_mfma_f32_16x16x32_bf16(a0, bj, acc[0][j], 0, 0, 0);
      acc[1][j] = __builtin_amdgcn_mfma_f32_16x16x32_bf16(a1, bj, acc[1][j], 0, 0, 0);
    }
    __syncthreads();
  }

#pragma unroll
  for (int t = 0; t < 2; ++t) {
#pragma unroll
    for (int j = 0; j < 4; ++j) {
      int col = col0 + 16 * j + m;
      float bv = bias ? bias[col] : 0.f;
#pragma unroll
      for (int rr = 0; rr < 4; ++rr) {
        int row = row0 + w * 32 + 16 * t + quad * 4 + rr;
        if (row >= M) continue;
        float v = acc[t][j][rr] + bv;
        if (RELU) v = fmaxf(v, 0.f);
        if (OUTBF)
          ((ushort_t*)Cout)[(size_t)row * Ncol + col] = f2bf(v);
        else
          ((float*)Cout)[(size_t)row * Ncol + col] = v;
      }
    }
  }
}

// ---------------------------------------------------------------------------
// FUSED edge phase (R7-proven): per-node online-softmax attention + V agg.
// One wave per node; half-wave (32 lanes) per edge slot => 2 edges in flight.
// L2-miss-path bound at ~3.7 TB/s (R7/R8 counters) — structural floor.
// ---------------------------------------------------------------------------
__global__ __launch_bounds__(256) void node_fused_k(
    const ushort_t* __restrict__ QKV, const float* __restrict__ ea,
    const float* __restrict__ We_l, const int* __restrict__ rowptr,
    const int* __restrict__ src_sorted, const int* __restrict__ eorig,
    ushort_t* __restrict__ agg, int n) {
  int node = (blockIdx.x * blockDim.x + threadIdx.x) >> 6;
  if (node >= n) return;
  int lane = threadIdx.x & 63;
  int hl = lane & 31;
  int slot = lane >> 5;
  ushort8v qu = *((const ushort8v*)(QKV + (size_t)node * 768) + hl);
  float q[8];
#pragma unroll
  for (int i = 0; i < 8; ++i) q[i] = bf2f(qu[i]);
  int start = rowptr[node], end = rowptr[node + 1];
  int hh = hl >> 2;
  float w0 = We_l[0 * 8 + hh], w1 = We_l[1 * 8 + hh], w2 = We_l[2 * 8 + hh];
  float m = -INFINITY, l = 0.f;
  float acc[8];
#pragma unroll
  for (int i = 0; i < 8; ++i) acc[i] = 0.f;

  int iters = (end - start + 1) >> 1;
  for (int it = 0; it < iters; ++it) {
    int p = start + 2 * it + slot;
    if (p < end) {
      int s = src_sorted[p];
      const ushort_t* base = QKV + (size_t)s * 768;
      ushort8v ku = *((const ushort8v*)(base + 256) + hl);
      ushort8v vu = *((const ushort8v*)(base + 512) + hl);
      float d = 0.f;
#pragma unroll
      for (int i = 0; i < 8; ++i) d += q[i] * bf2f(ku[i]);
      d += __shfl_xor(d, 1);
      d += __shfl_xor(d, 2);
      int e = eorig[p];
      float bias = ea[(size_t)e * 3 + 0] * w0 + ea[(size_t)e * 3 + 1] * w1 +
                   ea[(size_t)e * 3 + 2] * w2;
      float a = d * 0.17677669529663687f + bias;  // 1/sqrt(32)
      a = (a > 0.f) ? a : 0.2f * a;               // leaky_relu 0.2
      float mn = fmaxf(m, a);
      float sc = __expf(m - mn);
      float wv = __expf(a - mn);
      l = l * sc + wv;
#pragma unroll
      for (int i = 0; i < 8; ++i) acc[i] = acc[i] * sc + bf2f(vu[i]) * wv;
      m = mn;
    }
  }
  float m2 = __shfl_xor(m, 32);
  float l2 = __shfl_xor(l, 32);
  float mn = fmaxf(fmaxf(m, m2), -1e30f);
  float s1 = __expf(m - mn), s2 = __expf(m2 - mn);
  l = l * s1 + l2 * s2;
  float inv = 1.f / fmaxf(l, 1e-12f);
  ushort8v o;
#pragma unroll
  for (int i = 0; i < 8; ++i) {
    float v = (acc[i] * s1 + __shfl_xor(acc[i], 32) * s2) * inv;
    o[i] = f2bf(v);
  }
  if (slot == 0)
    *((ushort8v*)(agg + (size_t)node * 256) + hl) = o;
}

// ---------------------------------------------------------------------------
// h = LayerNorm(h + upd)*gamma+beta (in-place); also writes bf16 hbf
// ---------------------------------------------------------------------------
__global__ __launch_bounds__(256) void add_ln_k(
    float* __restrict__ h, const float* __restrict__ upd,
    const float* __restrict__ g, const float* __restrict__ b,
    ushort_t* __restrict__ hbf, int n) {
  int row = (blockIdx.x * blockDim.x + threadIdx.x) >> 6;
  if (row >= n) return;
  int lane = threadIdx.x & 63;
  float4 hv = ((const float4*)(h + (size_t)row * 256))[lane];
  float4 uv = ((const float4*)(upd + (size_t)row * 256))[lane];
  float4 s = make_float4(hv.x + uv.x, hv.y + uv.y, hv.z + uv.z, hv.w + uv.w);
  float sum = s.x + s.y + s.z + s.w;
  float sq = s.x * s.x + s.y * s.y + s.z * s.z + s.w * s.w;
  for (int d = 1; d < 64; d <<= 1) {
    sum += __shfl_xor(sum, d);
    sq += __shfl_xor(sq, d);
  }
  float mean = sum * (1.f / 256.f);
  float var = sq * (1.f / 256.f) - mean * mean;
  float r = rsqrtf(var + 1e-5f);
  float4 g4 = ((const float4*)g)[lane];
  float4 b4 = ((const float4*)b)[lane];
  float4 o;
  o.x = (s.x - mean) * r * g4.x + b4.x;
  o.y = (s.y - mean) * r * g4.y + b4.y;
  o.z = (s.z - mean) * r * g4.z + b4.z;
  o.w = (s.w - mean) * r * g4.w + b4.w;
  ((float4*)(h + (size_t)row * 256))[lane] = o;
  ushort4 ob;
  ob.x = f2bf(o.x);
  ob.y = f2bf(o.y);
  ob.z = f2bf(o.z);
  ob.w = f2bf(o.w);
  ((ushort4*)(hbf + (size_t)row * 256))[lane] = ob;
}

// ---------------------------------------------------------------------------
// out[n] = t[n,:128] @ W_h2 + b_h2 — one wave per row; fp32 out
// ---------------------------------------------------------------------------
__global__ __launch_bounds__(256) void head2_k(
    const float* __restrict__ t, const float* __restrict__ W2,
    const float* __restrict__ b2, float* __restrict__ out, int n) {
  int row = (blockIdx.x * blockDim.x + threadIdx.x) >> 6;
  if (row >= n) return;
  int lane = threadIdx.x & 63;
  float acc = t[(size_t)row * 128 + lane] * W2[lane] +
              t[(size_t)row * 128 + 64 + lane] * W2[64 + lane];
  for (int d = 1; d < 64; d <<= 1) acc += __shfl_xor(acc, d);
  if (lane == 0) out[row] = acc + b2[0];
}

// ---------------------------------------------------------------------------
extern "C" void kernel_launch(void* const* d_in, const int* in_sizes, int n_in,
                              void* d_out, int out_size, void* d_ws,
                              size_t ws_size, hipStream_t stream) {
  const float* x = (const float*)d_in[0];
  const float* edge_attr = (const float*)d_in[1];
  const float* W_in = (const float*)d_in[2];
  const float* b_in = (const float*)d_in[3];
  const float* Wq = (const float*)d_in[4];
  const float* Wk = (const float*)d_in[5];
  const float* Wv = (const float*)d_in[6];
  const float* We = (const float*)d_in[7];
  const float* Wo = (const float*)d_in[8];
  const float* bo = (const float*)d_in[9];
  const float* Wm = (const float*)d_in[10];
  const float* bm = (const float*)d_in[11];
  const float* gamma = (const float*)d_in[12];
  const float* beta = (const float*)d_in[13];
  const float* W_h1 = (const float*)d_in[14];
  const float* b_h1 = (const float*)d_in[15];
  const float* W_h2 = (const float*)d_in[16];
  const float* b_h2 = (const float*)d_in[17];
  const u32* eidx_w = (const u32*)d_in[18];

  // ws layout (~214 MB, proven-safe <= 238 MB)
  float* ws = (float*)d_ws;
  const size_t NH_ = (size_t)N_NODES * HDIM;
  float* h = ws;
  ushort_t* hbf = (ushort_t*)(h + NH_);
  ushort_t* QKVbf = hbf + NH_;              // N x 768
  ushort_t* aggbf = QKVbf + (size_t)N_NODES * 768;
  ushort_t* tmpbf = aggbf + NH_;
  float* Ub = (float*)QKVbf;                // N x 256 f32 (overlay)
  float* tH = (float*)QKVbf;                // N x 128 f32 (overlay)
  int* idxflag = (int*)(tmpbf + NH_);
  int* src_sorted = idxflag + 1;            // E
  int* eorig = src_sorted + E_EDGES;        // E
  int* rowptr = eorig + E_EDGES;            // N+1
  int* dcnt = rowptr + N_NODES + 1;         // N
  int* scanned = dcnt + N_NODES;            // N
  int* bsum = scanned + N_NODES;            // 256
  ushort_t* WT = (ushort_t*)(bsum + 256);
  const size_t W64K = (size_t)HDIM * HDIM;
  const size_t W128K = (size_t)2 * HDIM * HDIM;
  ushort_t* WqkvT = WT;                     // 3 layers x (768 x 256)
  ushort_t* WoT = WqkvT + 3 * 3 * W64K;
  ushort_t* WmT = WoT + 3 * W64K;
  ushort_t* Wh1T = WmT + 3 * W128K;
  // transient: consumed by fill_k before any GEMM writes QKVbf
  int* srcI = (int*)QKVbf;
  int* dstI = srcI + E_EDGES;

  detect_idx_k<<<1, 256, 0, stream>>>(eidx_w, idxflag);
  convert_idx_k<<<(E_EDGES + 255) / 256, 256, 0, stream>>>(
      eidx_w, idxflag, srcI, dstI, E_EDGES);

  // CSR build
  hipMemsetAsync(dcnt, 0, (size_t)N_NODES * sizeof(int), stream);
  hist_k<<<(E_EDGES + 255) / 256, 256, 0, stream>>>(dstI, dcnt, E_EDGES);
  const int nsb = (N_NODES + 255) / 256;
  scan1_k<<<nsb, 256, 0, stream>>>(dcnt, scanned, bsum, N_NODES);
  scan2_k<<<1, 256, 0, stream>>>(bsum, nsb);
  scan3_k<<<nsb, 256, 0, stream>>>(scanned, bsum, rowptr, N_NODES);
  hipMemsetAsync(dcnt, 0, (size_t)N_NODES * sizeof(int), stream);
  fill_k<<<(E_EDGES + 255) / 256, 256, 0, stream>>>(
      srcI, dstI, rowptr, dcnt, src_sorted, eorig, E_EDGES);

  // weight transpose+convert — 3 batched launches (was 16)
  wtrans_qkvo_k<<<dim3(16, 4, 12), 256, 0, stream>>>(Wq, Wk, Wv, Wo, WqkvT,
                                                     WoT);
  wtrans_k<<<dim3(32, 4, 3), 256, 0, stream>>>(Wm, WmT, 2 * HDIM, HDIM);
  wtrans_k<<<dim3(16, 2, 1), 256, 0, stream>>>(W_h1, Wh1T, HDIM, HDIM / 2);

  input_proj_k<<<(N_NODES + 31) / 32, 256, 0, stream>>>(x, W_in, b_in, h, hbf,
                                                        N_NODES);
  dim3 gqkv(768 / 64, (N_NODES + 127) / 128);  // (12, 391)
  dim3 gg(HDIM / 64, (N_NODES + 127) / 128);   // (4, 391)
  const int nodewave_grid = (N_NODES * 64 + 255) / 256;

  for (int l = 0; l < NLAYERS; ++l) {
    const float* We_l = We + (size_t)l * EDGED * NHEADS;
    const float* bo_l = bo + (size_t)l * HDIM;
    const float* bm_l = bm + (size_t)l * HDIM;

    // QKV = hbf @ [Wq|Wk|Wv]  (N x 768 bf16)
    gemm_mfma_k<false, false, true><<<gqkv, 256, 0, stream>>>(
        hbf, nullptr, WqkvT + (size_t)l * 3 * W64K, nullptr, QKVbf, N_NODES,
        HDIM, HDIM, 768);
    // fused attention + softmax + aggregation
    node_fused_k<<<nodewave_grid, 256, 0, stream>>>(
        QKVbf, edge_attr, We_l, rowptr, src_sorted, eorig, aggbf, N_NODES);
    // tmp = agg @ Wo + bo (bf16)
    gemm_mfma_k<false, false, true><<<gg, 256, 0, stream>>>(
        aggbf, nullptr, WoT + l * W64K, bo_l, tmpbf, N_NODES, HDIM, HDIM,
        HDIM);
    // upd = relu([hbf|tmpbf] @ Wm + bm) fp32 -> Ub (overlays QKVbf, dead)
    gemm_mfma_k<true, true, false><<<gg, 256, 0, stream>>>(
        hbf, tmpbf, WmT + l * W128K, bm_l, Ub, N_NODES, HDIM, 2 * HDIM, HDIM);
    add_ln_k<<<nodewave_grid, 256, 0, stream>>>(
        h, Ub, gamma + (size_t)l * HDIM, beta + (size_t)l * HDIM, hbf, N_NODES);
  }
  // head: t = relu(hbf @ W_h1 + b_h1) fp32 -> tH (overlays QKVbf)
  dim3 gh(2, (N_NODES + 127) / 128);
  gemm_mfma_k<false, true, false><<<gh, 256, 0, stream>>>(
      hbf, nullptr, Wh1T, b_h1, tH, N_NODES, HDIM, HDIM, HDIM / 2);
  head2_k<<<nodewave_grid, 256, 0, stream>>>(tH, W_h2, b_h2, (float*)d_out,
                                             N_NODES);
}

// Round 10
// 1092.977 us; speedup vs baseline: 1.1747x; 1.0536x over previous
//
#include <hip/hip_runtime.h>
#include <math.h>

#define N_NODES 50000
#define E_EDGES 800000
#define HDIM 256
#define NHEADS 8
#define HEADD 32
#define EDGED 3
#define NLAYERS 3

typedef unsigned int u32;
typedef unsigned short ushort_t;
typedef __attribute__((ext_vector_type(8))) short short8;
typedef __attribute__((ext_vector_type(8))) unsigned short ushort8v;
typedef __attribute__((ext_vector_type(4))) float float4v;

typedef __attribute__((address_space(1))) const void* gas_p;
typedef __attribute__((address_space(3))) void* las_p;

__device__ __forceinline__ float bf2f(ushort_t u) {
  union { u32 i; float f; } v;
  v.i = ((u32)u) << 16;
  return v.f;
}
// fp32 -> bf16 RNE
__device__ __forceinline__ ushort_t f2bf(float f) {
  u32 u = __float_as_uint(f);
  u = (u + 0x7FFF + ((u >> 16) & 1)) >> 16;
  return (ushort_t)u;
}

// ---------------------------------------------------------------------------
// edge_index layout detection (int64 vs int32 staging)
// ---------------------------------------------------------------------------
__global__ __launch_bounds__(256) void detect_idx_k(const u32* __restrict__ w,
                                                    int* __restrict__ flag) {
  __shared__ u32 sm[256];
  u32 mx = 0;
  for (int k = threadIdx.x; k < 4096; k += 256) mx = max(mx, w[2 * k + 1]);
  sm[threadIdx.x] = mx;
  __syncthreads();
  for (int s = 128; s > 0; s >>= 1) {
    if (threadIdx.x < s)
      sm[threadIdx.x] = max(sm[threadIdx.x], sm[threadIdx.x + s]);
    __syncthreads();
  }
  if (threadIdx.x == 0) flag[0] = (sm[0] == 0) ? 1 : 0;
}

// convert + dst histogram fused (saves a full E-sweep launch)
__global__ __launch_bounds__(256) void convert_hist_k(
    const u32* __restrict__ w, const int* __restrict__ flag,
    int* __restrict__ src32, int* __restrict__ dst32, int* __restrict__ dcnt,
    int E_) {
  int e = blockIdx.x * blockDim.x + threadIdx.x;
  if (e >= E_) return;
  int s, d;
  if (flag[0]) {
    s = (int)w[2 * e];
    d = (int)w[2 * (E_ + e)];
  } else {
    s = (int)w[e];
    d = (int)w[E_ + e];
  }
  src32[e] = s;
  dst32[e] = d;
  atomicAdd(&dcnt[d], 1);
}

__global__ __launch_bounds__(256) void scan1_k(const int* __restrict__ deg,
                                               int* __restrict__ scanned,
                                               int* __restrict__ bsum, int n) {
  __shared__ int tmp[256];
  int tid = threadIdx.x;
  int i = blockIdx.x * 256 + tid;
  tmp[tid] = (i < n) ? deg[i] : 0;
  __syncthreads();
  for (int off = 1; off < 256; off <<= 1) {
    int t = (tid >= off) ? tmp[tid - off] : 0;
    __syncthreads();
    tmp[tid] += t;
    __syncthreads();
  }
  if (i < n) scanned[i] = tmp[tid];
  if (tid == 255) bsum[blockIdx.x] = tmp[255];
}

__global__ __launch_bounds__(256) void scan2_k(int* __restrict__ bsum, int nb) {
  __shared__ int tmp[256];
  int tid = threadIdx.x;
  tmp[tid] = (tid < nb) ? bsum[tid] : 0;
  __syncthreads();
  for (int off = 1; off < 256; off <<= 1) {
    int t = (tid >= off) ? tmp[tid - off] : 0;
    __syncthreads();
    tmp[tid] += t;
    __syncthreads();
  }
  if (tid < nb) bsum[tid] = tmp[tid];
}

__global__ __launch_bounds__(256) void scan3_k(const int* __restrict__ scanned,
                                               const int* __restrict__ bsum,
                                               int* __restrict__ rowptr, int n) {
  int i = blockIdx.x * 256 + threadIdx.x;
  if (i < n)
    rowptr[i + 1] = scanned[i] + (blockIdx.x > 0 ? bsum[blockIdx.x - 1] : 0);
  if (i == 0) rowptr[0] = 0;
}

__global__ __launch_bounds__(256) void fill_k(
    const int* __restrict__ srcI, const int* __restrict__ dstI,
    const int* __restrict__ rowptr, int* __restrict__ cursor,
    int* __restrict__ src_sorted, int* __restrict__ eorig, int E_) {
  int e = blockIdx.x * blockDim.x + threadIdx.x;
  if (e >= E_) return;
  int d = dstI[e];
  int p = rowptr[d] + atomicAdd(&cursor[d], 1);
  src_sorted[p] = srcI[e];
  eorig[p] = e;
}

// ---------------------------------------------------------------------------
// Weight transpose+convert: W (K x N fp32) -> WT (N x K bf16), tile 16k x 64n
// blockIdx.z = matrix index.
// ---------------------------------------------------------------------------
__global__ __launch_bounds__(256) void wtrans_k(const float* __restrict__ W,
                                                ushort_t* __restrict__ WT,
                                                int K, int N) {
  W += (size_t)blockIdx.z * K * N;
  WT += (size_t)blockIdx.z * N * K;
  __shared__ float t[64][17];
  int k0 = blockIdx.x * 16, n0 = blockIdx.y * 64;
  int tid = threadIdx.x;
  int r = tid >> 6, c = tid & 63;
#pragma unroll
  for (int i = 0; i < 4; ++i)
    t[c][r + 4 * i] = W[(size_t)(k0 + r + 4 * i) * N + n0 + c];
  __syncthreads();
  int n = tid >> 2, j4 = (tid & 3) * 4;
  ushort4 o;
  o.x = f2bf(t[n][j4 + 0]);
  o.y = f2bf(t[n][j4 + 1]);
  o.z = f2bf(t[n][j4 + 2]);
  o.w = f2bf(t[n][j4 + 3]);
  *(ushort4*)&WT[(size_t)(n0 + n) * K + k0 + j4] = o;
}

// batched Wq/Wk/Wv/Wo transpose: blockIdx.z = l*4 + m (m: 0=q,1=k,2=v,3=o)
__global__ __launch_bounds__(256) void wtrans_qkvo_k(
    const float* __restrict__ Wq, const float* __restrict__ Wk,
    const float* __restrict__ Wv, const float* __restrict__ Wo,
    ushort_t* __restrict__ WqkvT, ushort_t* __restrict__ WoT) {
  const size_t W64K = 65536;
  int z = blockIdx.z, l = z >> 2, m = z & 3;
  const float* W =
      (m == 0 ? Wq : m == 1 ? Wk : m == 2 ? Wv : Wo) + (size_t)l * W64K;
  ushort_t* WT = (m < 3) ? (WqkvT + ((size_t)l * 3 + m) * W64K)
                         : (WoT + (size_t)l * W64K);
  __shared__ float t[64][17];
  int k0 = blockIdx.x * 16, n0 = blockIdx.y * 64;
  int tid = threadIdx.x;
  int r = tid >> 6, c = tid & 63;
#pragma unroll
  for (int i = 0; i < 4; ++i)
    t[c][r + 4 * i] = W[(size_t)(k0 + r + 4 * i) * 256 + n0 + c];
  __syncthreads();
  int n = tid >> 2, j4 = (tid & 3) * 4;
  ushort4 o;
  o.x = f2bf(t[n][j4 + 0]);
  o.y = f2bf(t[n][j4 + 1]);
  o.z = f2bf(t[n][j4 + 2]);
  o.w = f2bf(t[n][j4 + 3]);
  *(ushort4*)&WT[(size_t)(n0 + n) * 256 + k0 + j4] = o;
}

// ---------------------------------------------------------------------------
// Input projection: h = relu(x @ W_in + b_in); writes fp32 h AND bf16 hbf
// ---------------------------------------------------------------------------
__global__ __launch_bounds__(256) void input_proj_k(
    const float* __restrict__ x, const float* __restrict__ W,
    const float* __restrict__ b, float* __restrict__ h,
    ushort_t* __restrict__ hbf, int n) {
  __shared__ float ws[10 * 256];
  __shared__ float bs[256];
  int tid = threadIdx.x;
  for (int i = tid; i < 2560; i += 256) ws[i] = W[i];
  bs[tid] = b[tid];
  __syncthreads();
  int row0 = blockIdx.x * 32;
  for (int rr = 0; rr < 32; ++rr) {
    int row = row0 + rr;
    if (row >= n) break;
    float acc = bs[tid];
#pragma unroll
    for (int i = 0; i < 10; ++i) acc += x[row * 10 + i] * ws[i * 256 + tid];
    acc = fmaxf(acc, 0.f);
    h[(size_t)row * 256 + tid] = acc;
    hbf[(size_t)row * 256 + tid] = f2bf(acc);
  }
}

// ---------------------------------------------------------------------------
// bf16 MFMA GEMM, 128x64 tile, BK=64 (half the barrier drains of R9's BK=32),
// async global_load_lds width=16 staging throughout.
// A1 (M x K1 bf16 row-major); if CONCAT logical A = [A1|A2], Ktot = 2*K1
// (K1 % 64 == 0 so a BK chunk never straddles the concat boundary).
// BT (Ncol x Ktot bf16, n-major k-contig). bias fp32 or null.
// LDS: Als row stride 64 elems (128 B): staged dest byte = q*4096 + tid*16
// == wave-uniform (w*1024 + q*4096) + lane*16. OOB rows exec-masked; their
// stale LDS rows only affect discarded C rows (row-independent dot products).
// ---------------------------------------------------------------------------
template <bool CONCAT, bool RELU, bool OUTBF>
__global__ __launch_bounds__(256) void gemm_mfma_k(
    const ushort_t* __restrict__ A1, const ushort_t* __restrict__ A2,
    const ushort_t* __restrict__ BT, const float* __restrict__ bias,
    void* __restrict__ Cout, int M, int K1, int Ktot, int Ncol) {
  __shared__ __align__(16) ushort_t Als[128 * 64];  // 16 KB
  __shared__ __align__(16) ushort_t Bls[64 * 64];   // 8 KB
  int tid = threadIdx.x;
  int lane = tid & 63, w = tid >> 6;
  int quad = lane >> 4, m = lane & 15;
  int row0 = blockIdx.y * 128, col0 = blockIdx.x * 64;
  float4v acc[2][4];
#pragma unroll
  for (int t = 0; t < 2; ++t)
#pragma unroll
    for (int j = 0; j < 4; ++j) acc[t][j] = (float4v){0.f, 0.f, 0.f, 0.f};

  int srow = tid >> 3;      // 0..31 staging row within 32-row group
  int skc = (tid & 7) * 8;  // k elem offset (8 ushorts = 16 B)
  char* alsb = (char*)Als + w * 1024;  // wave-uniform LDS base
  char* blsb = (char*)Bls + w * 1024;

  for (int k0 = 0; k0 < Ktot; k0 += 64) {
    const ushort_t* Ap = A1;
    int kk = k0;
    if (CONCAT && k0 >= K1) { Ap = A2; kk = k0 - K1; }
#pragma unroll
    for (int q = 0; q < 4; ++q) {
      int r = row0 + q * 32 + srow;
      if (r < M) {
        const ushort_t* g = Ap + (size_t)r * K1 + kk + skc;
        __builtin_amdgcn_global_load_lds((gas_p)g, (las_p)(alsb + q * 4096),
                                         16, 0, 0);
      }
    }
#pragma unroll
    for (int q = 0; q < 2; ++q) {
      const ushort_t* g = BT + (size_t)(col0 + q * 32 + srow) * Ktot + k0 + skc;
      __builtin_amdgcn_global_load_lds((gas_p)g, (las_p)(blsb + q * 4096), 16,
                                       0, 0);
    }
    __syncthreads();
#pragma unroll
    for (int ks = 0; ks < 64; ks += 32) {
      short8 a0 = *(const short8*)&Als[(w * 32 + m) * 64 + ks + quad * 8];
      short8 a1 = *(const short8*)&Als[(w * 32 + 16 + m) * 64 + ks + quad * 8];
#pragma unroll
      for (int j = 0; j < 4; ++j) {
        short8 bj = *(const short8*)&Bls[(16 * j + m) * 64 + ks + quad * 8];
        acc[0][j] =
            __builtin_amdgcn_mfma_f32_16x16x32_bf16(a0, bj, acc[0][j], 0, 0, 0);
        acc[1][j] =
            __builtin_amdgcn_mfma_f32_16x16x32_bf16(a1, bj, acc[1][j], 0, 0, 0);
      }
    }
    __syncthreads();
  }

#pragma unroll
  for (int t = 0; t < 2; ++t) {
#pragma unroll
    for (int j = 0; j < 4; ++j) {
      int col = col0 + 16 * j + m;
      float bv = bias ? bias[col] : 0.f;
#pragma unroll
      for (int rr = 0; rr < 4; ++rr) {
        int row = row0 + w * 32 + 16 * t + quad * 4 + rr;
        if (row >= M) continue;
        float v = acc[t][j][rr] + bv;
        if (RELU) v = fmaxf(v, 0.f);
        if (OUTBF)
          ((ushort_t*)Cout)[(size_t)row * Ncol + col] = f2bf(v);
        else
          ((float*)Cout)[(size_t)row * Ncol + col] = v;
      }
    }
  }
}

// ---------------------------------------------------------------------------
// FUSED edge phase (R7-proven): per-node online-softmax attention + V agg.
// L2-miss-path bound at ~3.7 TB/s (R7-R9 counters) — structural floor.
// ---------------------------------------------------------------------------
__global__ __launch_bounds__(256) void node_fused_k(
    const ushort_t* __restrict__ QKV, const float* __restrict__ ea,
    const float* __restrict__ We_l, const int* __restrict__ rowptr,
    const int* __restrict__ src_sorted, const int* __restrict__ eorig,
    ushort_t* __restrict__ agg, int n) {
  int node = (blockIdx.x * blockDim.x + threadIdx.x) >> 6;
  if (node >= n) return;
  int lane = threadIdx.x & 63;
  int hl = lane & 31;
  int slot = lane >> 5;
  ushort8v qu = *((const ushort8v*)(QKV + (size_t)node * 768) + hl);
  float q[8];
#pragma unroll
  for (int i = 0; i < 8; ++i) q[i] = bf2f(qu[i]);
  int start = rowptr[node], end = rowptr[node + 1];
  int hh = hl >> 2;
  float w0 = We_l[0 * 8 + hh], w1 = We_l[1 * 8 + hh], w2 = We_l[2 * 8 + hh];
  float m = -INFINITY, l = 0.f;
  float acc[8];
#pragma unroll
  for (int i = 0; i < 8; ++i) acc[i] = 0.f;

  int iters = (end - start + 1) >> 1;
  for (int it = 0; it < iters; ++it) {
    int p = start + 2 * it + slot;
    if (p < end) {
      int s = src_sorted[p];
      const ushort_t* base = QKV + (size_t)s * 768;
      ushort8v ku = *((const ushort8v*)(base + 256) + hl);
      ushort8v vu = *((const ushort8v*)(base + 512) + hl);
      float d = 0.f;
#pragma unroll
      for (int i = 0; i < 8; ++i) d += q[i] * bf2f(ku[i]);
      d += __shfl_xor(d, 1);
      d += __shfl_xor(d, 2);
      int e = eorig[p];
      float bias = ea[(size_t)e * 3 + 0] * w0 + ea[(size_t)e * 3 + 1] * w1 +
                   ea[(size_t)e * 3 + 2] * w2;
      float a = d * 0.17677669529663687f + bias;  // 1/sqrt(32)
      a = (a > 0.f) ? a : 0.2f * a;               // leaky_relu 0.2
      float mn = fmaxf(m, a);
      float sc = __expf(m - mn);
      float wv = __expf(a - mn);
      l = l * sc + wv;
#pragma unroll
      for (int i = 0; i < 8; ++i) acc[i] = acc[i] * sc + bf2f(vu[i]) * wv;
      m = mn;
    }
  }
  float m2 = __shfl_xor(m, 32);
  float l2 = __shfl_xor(l, 32);
  float mn = fmaxf(fmaxf(m, m2), -1e30f);
  float s1 = __expf(m - mn), s2 = __expf(m2 - mn);
  l = l * s1 + l2 * s2;
  float inv = 1.f / fmaxf(l, 1e-12f);
  ushort8v o;
#pragma unroll
  for (int i = 0; i < 8; ++i) {
    float v = (acc[i] * s1 + __shfl_xor(acc[i], 32) * s2) * inv;
    o[i] = f2bf(v);
  }
  if (slot == 0)
    *((ushort8v*)(agg + (size_t)node * 256) + hl) = o;
}

// ---------------------------------------------------------------------------
// h = LayerNorm(h + upd)*gamma+beta; upd is bf16 now; also writes bf16 hbf
// ---------------------------------------------------------------------------
__global__ __launch_bounds__(256) void add_ln_k(
    float* __restrict__ h, const ushort_t* __restrict__ upd,
    const float* __restrict__ g, const float* __restrict__ b,
    ushort_t* __restrict__ hbf, int n) {
  int row = (blockIdx.x * blockDim.x + threadIdx.x) >> 6;
  if (row >= n) return;
  int lane = threadIdx.x & 63;
  float4 hv = ((const float4*)(h + (size_t)row * 256))[lane];
  ushort4 uu = ((const ushort4*)(upd + (size_t)row * 256))[lane];
  float4 s = make_float4(hv.x + bf2f(uu.x), hv.y + bf2f(uu.y),
                         hv.z + bf2f(uu.z), hv.w + bf2f(uu.w));
  float sum = s.x + s.y + s.z + s.w;
  float sq = s.x * s.x + s.y * s.y + s.z * s.z + s.w * s.w;
  for (int d = 1; d < 64; d <<= 1) {
    sum += __shfl_xor(sum, d);
    sq += __shfl_xor(sq, d);
  }
  float mean = sum * (1.f / 256.f);
  float var = sq * (1.f / 256.f) - mean * mean;
  float r = rsqrtf(var + 1e-5f);
  float4 g4 = ((const float4*)g)[lane];
  float4 b4 = ((const float4*)b)[lane];
  float4 o;
  o.x = (s.x - mean) * r * g4.x + b4.x;
  o.y = (s.y - mean) * r * g4.y + b4.y;
  o.z = (s.z - mean) * r * g4.z + b4.z;
  o.w = (s.w - mean) * r * g4.w + b4.w;
  ((float4*)(h + (size_t)row * 256))[lane] = o;
  ushort4 ob;
  ob.x = f2bf(o.x);
  ob.y = f2bf(o.y);
  ob.z = f2bf(o.z);
  ob.w = f2bf(o.w);
  ((ushort4*)(hbf + (size_t)row * 256))[lane] = ob;
}

// ---------------------------------------------------------------------------
// out[n] = t[n,:128] @ W_h2 + b_h2 — one wave per row; fp32 out
// ---------------------------------------------------------------------------
__global__ __launch_bounds__(256) void head2_k(
    const float* __restrict__ t, const float* __restrict__ W2,
    const float* __restrict__ b2, float* __restrict__ out, int n) {
  int row = (blockIdx.x * blockDim.x + threadIdx.x) >> 6;
  if (row >= n) return;
  int lane = threadIdx.x & 63;
  float acc = t[(size_t)row * 128 + lane] * W2[lane] +
              t[(size_t)row * 128 + 64 + lane] * W2[64 + lane];
  for (int d = 1; d < 64; d <<= 1) acc += __shfl_xor(acc, d);
  if (lane == 0) out[row] = acc + b2[0];
}

// ---------------------------------------------------------------------------
extern "C" void kernel_launch(void* const* d_in, const int* in_sizes, int n_in,
                              void* d_out, int out_size, void* d_ws,
                              size_t ws_size, hipStream_t stream) {
  const float* x = (const float*)d_in[0];
  const float* edge_attr = (const float*)d_in[1];
  const float* W_in = (const float*)d_in[2];
  const float* b_in = (const float*)d_in[3];
  const float* Wq = (const float*)d_in[4];
  const float* Wk = (const float*)d_in[5];
  const float* Wv = (const float*)d_in[6];
  const float* We = (const float*)d_in[7];
  const float* Wo = (const float*)d_in[8];
  const float* bo = (const float*)d_in[9];
  const float* Wm = (const float*)d_in[10];
  const float* bm = (const float*)d_in[11];
  const float* gamma = (const float*)d_in[12];
  const float* beta = (const float*)d_in[13];
  const float* W_h1 = (const float*)d_in[14];
  const float* b_h1 = (const float*)d_in[15];
  const float* W_h2 = (const float*)d_in[16];
  const float* b_h2 = (const float*)d_in[17];
  const u32* eidx_w = (const u32*)d_in[18];

  // ws layout (~214 MB, proven-safe <= 238 MB)
  float* ws = (float*)d_ws;
  const size_t NH_ = (size_t)N_NODES * HDIM;
  float* h = ws;
  ushort_t* hbf = (ushort_t*)(h + NH_);
  ushort_t* QKVbf = hbf + NH_;              // N x 768
  ushort_t* aggbf = QKVbf + (size_t)N_NODES * 768;
  ushort_t* tmpbf = aggbf + NH_;
  ushort_t* Ubbf = QKVbf;                   // N x 256 bf16 upd (overlay; QKV dead)
  float* tH = (float*)QKVbf;                // N x 128 f32 head (overlay)
  int* idxflag = (int*)(tmpbf + NH_);
  int* src_sorted = idxflag + 1;            // E
  int* eorig = src_sorted + E_EDGES;        // E
  int* rowptr = eorig + E_EDGES;            // N+1
  int* dcnt = rowptr + N_NODES + 1;         // N (hist)
  int* cursor = dcnt + N_NODES;             // N (fill) — zeroed together
  int* scanned = cursor + N_NODES;          // N
  int* bsum = scanned + N_NODES;            // 256
  ushort_t* WT = (ushort_t*)(bsum + 256);
  const size_t W64K = (size_t)HDIM * HDIM;
  const size_t W128K = (size_t)2 * HDIM * HDIM;
  ushort_t* WqkvT = WT;                     // 3 layers x (768 x 256)
  ushort_t* WoT = WqkvT + 3 * 3 * W64K;
  ushort_t* WmT = WoT + 3 * W64K;
  ushort_t* Wh1T = WmT + 3 * W128K;
  // transient: consumed by fill_k before any GEMM writes QKVbf
  int* srcI = (int*)QKVbf;
  int* dstI = srcI + E_EDGES;

  detect_idx_k<<<1, 256, 0, stream>>>(eidx_w, idxflag);
  // CSR build (convert+hist fused; one memset covers dcnt and cursor)
  hipMemsetAsync(dcnt, 0, (size_t)2 * N_NODES * sizeof(int), stream);
  convert_hist_k<<<(E_EDGES + 255) / 256, 256, 0, stream>>>(
      eidx_w, idxflag, srcI, dstI, dcnt, E_EDGES);
  const int nsb = (N_NODES + 255) / 256;
  scan1_k<<<nsb, 256, 0, stream>>>(dcnt, scanned, bsum, N_NODES);
  scan2_k<<<1, 256, 0, stream>>>(bsum, nsb);
  scan3_k<<<nsb, 256, 0, stream>>>(scanned, bsum, rowptr, N_NODES);
  fill_k<<<(E_EDGES + 255) / 256, 256, 0, stream>>>(
      srcI, dstI, rowptr, cursor, src_sorted, eorig, E_EDGES);

  // weight transpose+convert — 3 batched launches
  wtrans_qkvo_k<<<dim3(16, 4, 12), 256, 0, stream>>>(Wq, Wk, Wv, Wo, WqkvT,
                                                     WoT);
  wtrans_k<<<dim3(32, 4, 3), 256, 0, stream>>>(Wm, WmT, 2 * HDIM, HDIM);
  wtrans_k<<<dim3(16, 2, 1), 256, 0, stream>>>(W_h1, Wh1T, HDIM, HDIM / 2);

  input_proj_k<<<(N_NODES + 31) / 32, 256, 0, stream>>>(x, W_in, b_in, h, hbf,
                                                        N_NODES);
  dim3 gqkv(768 / 64, (N_NODES + 127) / 128);  // (12, 391)
  dim3 gg(HDIM / 64, (N_NODES + 127) / 128);   // (4, 391)
  const int nodewave_grid = (N_NODES * 64 + 255) / 256;

  for (int l = 0; l < NLAYERS; ++l) {
    const float* We_l = We + (size_t)l * EDGED * NHEADS;
    const float* bo_l = bo + (size_t)l * HDIM;
    const float* bm_l = bm + (size_t)l * HDIM;

    // QKV = hbf @ [Wq|Wk|Wv]  (N x 768 bf16)
    gemm_mfma_k<false, false, true><<<gqkv, 256, 0, stream>>>(
        hbf, nullptr, WqkvT + (size_t)l * 3 * W64K, nullptr, QKVbf, N_NODES,
        HDIM, HDIM, 768);
    // fused attention + softmax + aggregation
    node_fused_k<<<nodewave_grid, 256, 0, stream>>>(
        QKVbf, edge_attr, We_l, rowptr, src_sorted, eorig, aggbf, N_NODES);
    // tmp = agg @ Wo + bo (bf16)
    gemm_mfma_k<false, false, true><<<gg, 256, 0, stream>>>(
        aggbf, nullptr, WoT + l * W64K, bo_l, tmpbf, N_NODES, HDIM, HDIM,
        HDIM);
    // upd = relu([hbf|tmpbf] @ Wm + bm) -> bf16 Ubbf (overlays QKVbf, dead)
    gemm_mfma_k<true, true, true><<<gg, 256, 0, stream>>>(
        hbf, tmpbf, WmT + l * W128K, bm_l, Ubbf, N_NODES, HDIM, 2 * HDIM,
        HDIM);
    add_ln_k<<<nodewave_grid, 256, 0, stream>>>(
        h, Ubbf, gamma + (size_t)l * HDIM, beta + (size_t)l * HDIM, hbf,
        N_NODES);
  }
  // head: t = relu(hbf @ W_h1 + b_h1) fp32 -> tH (overlays QKVbf)
  dim3 gh(2, (N_NODES + 127) / 128);
  gemm_mfma_k<false, true, false><<<gh, 256, 0, stream>>>(
      hbf, nullptr, Wh1T, b_h1, tH, N_NODES, HDIM, HDIM, HDIM / 2);
  head2_k<<<nodewave_grid, 256, 0, stream>>>(tH, W_h2, b_h2, (float*)d_out,
                                             N_NODES);
}